// Round 5
// baseline (2863.940 us; speedup 1.0000x reference)
//
#include <hip/hip_runtime.h>
#include <hip/hip_bf16.h>

// Bidirectional LSTM, B=32 T=512 D=H=512. f32 I/O, bf16 MFMA internally.
//
// Fast path (ws_size >= ~269 MB):
//   xproj:    P[dir][t][b][2048-permuted] = x@Wih^T + b_ih  (parallel MFMA GEMM,
//             512 wgs, 2 slices/wg; reuses the proven fused staging/MFMA code)
//   lstm_rec: persistent, grid=(32 slices, 2 dirs); per step only h@Whh^T
//             (32 MFMAs/wave), P prefetched behind the barrier wait.
//   Barrier:  FLAG ARRAY (no RMW): wg s stores flags[dir][s]=step+1 (relaxed
//             agent, distinct dwords in one 128B line); wave0 lanes0..31 poll
//             all 32 flags with one parallel coherent load + __all.
// Fallback (small ws): R4's proven fused kernel (x staged per step).

typedef __bf16 bf16;
typedef __attribute__((ext_vector_type(8))) __bf16 bf16x8;
typedef __attribute__((ext_vector_type(4))) float f32x4;

__device__ __forceinline__ float sigmoidf_(float x) {
  return 1.f / (1.f + __expf(-x));
}
__device__ __forceinline__ float tanhf_(float x) {
  float e = __expf(-2.f * fabsf(x));
  return copysignf((1.f - e) / (1.f + e), x);
}
__device__ __forceinline__ unsigned ald(const unsigned* p) {
  return __hip_atomic_load(p, __ATOMIC_RELAXED, __HIP_MEMORY_SCOPE_AGENT);
}
__device__ __forceinline__ void ast(unsigned* p, unsigned v) {
  __hip_atomic_store(p, v, __ATOMIC_RELAXED, __HIP_MEMORY_SCOPE_AGENT);
}
__device__ __forceinline__ bf16x8 cvt8v(float4 a, float4 b) {
  bf16x8 v;
  v[0] = (bf16)a.x; v[1] = (bf16)a.y; v[2] = (bf16)a.z; v[3] = (bf16)a.w;
  v[4] = (bf16)b.x; v[5] = (bf16)b.y; v[6] = (bf16)b.z; v[7] = (bf16)b.w;
  return v;
}

// ---------------- lengths ----------------
__global__ void lengths_kernel(const int* __restrict__ mask, int* __restrict__ lengths) {
  __shared__ int part[32][8];
  int t = threadIdx.x;
  int b = t >> 3, sub = t & 7;
  int s = 0;
#pragma unroll 8
  for (int k = 0; k < 64; ++k) s += mask[b * 512 + sub + 8 * k];
  part[b][sub] = s;
  __syncthreads();
  if (sub == 0) {
    int tot = 0;
#pragma unroll
    for (int k = 0; k < 8; ++k) tot += part[b][k];
    lengths[b] = tot;
  }
}

// ---------------- xproj: P = x @ Wih^T + b (permuted layout) ----------------
// grid (16, 2, 16): bx -> slices {2bx, 2bx+1}, dir, 32 t's per wg.
// P row = (dir*512 + t)*32 + b ; col = s*64 + (colpair)*8 + gate*2 + parity.
__global__ __launch_bounds__(256, 1) void xproj(
    const float* __restrict__ x,
    const float* __restrict__ Wih_f, const float* __restrict__ bih_f,
    const float* __restrict__ Wih_b, const float* __restrict__ bih_b,
    float* __restrict__ P) {
  const int bx = blockIdx.x;
  const int dir = blockIdx.y;
  const int tt0 = blockIdx.z * 32;
  const float* Wih = dir ? Wih_b : Wih_f;
  const float* bih = dir ? bih_b : bih_f;
  const int tid = threadIdx.x;
  const int lane = tid & 63, wave = tid >> 6;
  const int l15 = lane & 15, quad = lane >> 4;

  __shared__ __align__(16) bf16 xA[32 * 512];

  bf16x8 wih[2][16];
  float bv[2];
#pragma unroll
  for (int sl = 0; sl < 2; ++sl) {
    int grow = wave * 512 + (bx * 2 + sl) * 16 + l15;
#pragma unroll
    for (int k = 0; k < 16; ++k) {
      const float* pw = Wih + (size_t)grow * 512 + k * 32 + quad * 8;
      wih[sl][k] = cvt8v(*(const float4*)pw, *(const float4*)(pw + 4));
    }
    bv[sl] = bih[grow];
  }

  for (int tt = 0; tt < 32; ++tt) {
    int t = tt0 + tt;
    // stage x[b=0..31][t][:] -> swizzled bf16 LDS (proven pattern)
#pragma unroll
    for (int i = 0; i < 8; ++i) {
      int c = i * 256 + tid;
      int m = c >> 6, kbp = c & 63;
      int kb = kbp ^ (m & 7);
      const float4* p = (const float4*)(x + ((size_t)m * 512 + t) * 512 + kb * 8);
      *(bf16x8*)(xA + c * 8) = cvt8v(p[0], p[1]);
    }
    __syncthreads();
    f32x4 acc[2][2];
#pragma unroll
    for (int sl = 0; sl < 2; ++sl) {
      acc[sl][0] = (f32x4){bv[sl], bv[sl], bv[sl], bv[sl]};
      acc[sl][1] = (f32x4){bv[sl], bv[sl], bv[sl], bv[sl]};
    }
#pragma unroll
    for (int k = 0; k < 16; ++k) {
      int kb = k * 4 + quad;
      int sw = (kb ^ (l15 & 7)) * 8;
      bf16x8 a0 = *(const bf16x8*)(xA + l15 * 512 + sw);
      bf16x8 a1 = *(const bf16x8*)(xA + (16 + l15) * 512 + sw);
#pragma unroll
      for (int sl = 0; sl < 2; ++sl) {
        acc[sl][0] = __builtin_amdgcn_mfma_f32_16x16x32_bf16(a0, wih[sl][k], acc[sl][0], 0, 0, 0);
        acc[sl][1] = __builtin_amdgcn_mfma_f32_16x16x32_bf16(a1, wih[sl][k], acc[sl][1], 0, 0, 0);
      }
    }
    __syncthreads();   // protect xA before next-iter staging
    size_t rowb = (size_t)(dir * 512 + t) * 32;
#pragma unroll
    for (int sl = 0; sl < 2; ++sl) {
      int off = (bx * 2 + sl) * 64 + (l15 >> 1) * 8 + wave * 2 + (l15 & 1);
#pragma unroll
      for (int r = 0; r < 4; ++r) {
        P[(rowb + quad * 4 + r) * 2048 + off] = acc[sl][0][r];
        P[(rowb + 16 + quad * 4 + r) * 2048 + off] = acc[sl][1][r];
      }
    }
  }
}

// ---------------- persistent recurrence (P path) ----------------
__global__ __launch_bounds__(256, 1) void lstm_rec(
    const float* __restrict__ Whh_f, const float* __restrict__ Whh_b,
    const float* __restrict__ P,
    const int* __restrict__ lengths,
    unsigned* __restrict__ hbuf,        // [2 dir][2 par][32][256] dwords
    unsigned* __restrict__ flags,       // [2][32] dwords (dirs 128 B apart)
    float* __restrict__ out) {          // [32][512][1024] f32
  const int s = blockIdx.x;
  const int dir = blockIdx.y;
  const float* Whh = dir ? Whh_b : Whh_f;
  unsigned* flg = flags + dir * 32;

  const int tid = threadIdx.x;
  const int lane = tid & 63, wave = tid >> 6;
  const int l15 = lane & 15, quad = lane >> 4;

  __shared__ __align__(16) bf16 hA[32 * 512];
  __shared__ float vbuf[4][32][17];
  __shared__ int lenL[32];

  bf16x8 whh[16];
  {
    int grow = wave * 512 + s * 16 + l15;
#pragma unroll
    for (int k = 0; k < 16; ++k) {
      const float* ph = Whh + (size_t)grow * 512 + k * 32 + quad * 8;
      whh[k] = cvt8v(*(const float4*)ph, *(const float4*)(ph + 4));
    }
  }
  if (tid < 32) lenL[tid] = lengths[tid];
  __syncthreads();

  const int cb = tid >> 3, cjj = tid & 7, cj = cjj * 2;
  float creg0 = 0.f, creg1 = 0.f;
  unsigned* hb = hbuf + dir * (2 * 32 * 256);

  // initial P prefetch (step 0)
  int trc = dir ? ((511 + lenL[cb]) & 511) : 0;
  float4 p0, p1;
  {
    const float* Pp = P + ((size_t)(dir * 512 + trc) * 32 + cb) * 2048 + s * 64 + cjj * 8;
    p0 = ((const float4*)Pp)[0];
    p1 = ((const float4*)Pp)[1];
  }

  for (int step = 0; step < 512; ++step) {
    const int par = step & 1;
    const unsigned* hprev = hb + par * (32 * 256);
    unsigned* hnext = hb + (par ^ 1) * (32 * 256);

    // stage h[32][512] bf16 -> swizzled LDS via coherent dword loads
#pragma unroll
    for (int i = 0; i < 8; ++i) {
      int c = i * 256 + tid;
      int m = c >> 6, kbp = c & 63;
      int kb = kbp ^ (m & 7);
      const unsigned* hp = hprev + m * 256 + kb * 4;
      uint4 d;
      d.x = ald(hp); d.y = ald(hp + 1); d.z = ald(hp + 2); d.w = ald(hp + 3);
      *(uint4*)(hA + c * 8) = d;
    }
    __syncthreads();

    // v = h @ Whh^T (P added at cell update)
    f32x4 acc0 = {}, acc1 = {};
#pragma unroll
    for (int k = 0; k < 16; ++k) {
      int kb = k * 4 + quad;
      int sw = (kb ^ (l15 & 7)) * 8;
      bf16x8 ah0 = *(const bf16x8*)(hA + l15 * 512 + sw);
      bf16x8 ah1 = *(const bf16x8*)(hA + (16 + l15) * 512 + sw);
      acc0 = __builtin_amdgcn_mfma_f32_16x16x32_bf16(ah0, whh[k], acc0, 0, 0, 0);
      acc1 = __builtin_amdgcn_mfma_f32_16x16x32_bf16(ah1, whh[k], acc1, 0, 0, 0);
    }
#pragma unroll
    for (int r = 0; r < 4; ++r) {
      vbuf[wave][quad * 4 + r][l15] = acc0[r];
      vbuf[wave][16 + quad * 4 + r][l15] = acc1[r];
    }
    __syncthreads();

    // cell update (thread owns (cb, cj), (cb, cj+1))
    float i0 = vbuf[0][cb][cj] + p0.x, i1 = vbuf[0][cb][cj + 1] + p0.y;
    float f0 = vbuf[1][cb][cj] + p0.z, f1 = vbuf[1][cb][cj + 1] + p0.w;
    float g0 = vbuf[2][cb][cj] + p1.x, g1 = vbuf[2][cb][cj + 1] + p1.y;
    float o0 = vbuf[3][cb][cj] + p1.z, o1 = vbuf[3][cb][cj + 1] + p1.w;
    float c0 = sigmoidf_(f0) * creg0 + sigmoidf_(i0) * tanhf_(g0);
    float c1 = sigmoidf_(f1) * creg1 + sigmoidf_(i1) * tanhf_(g1);
    creg0 = c0; creg1 = c1;
    float h0 = tanhf_(c0) * sigmoidf_(o0);
    float h1 = tanhf_(c1) * sigmoidf_(o1);
    unsigned ulo = (unsigned)__builtin_bit_cast(unsigned short, (bf16)h0);
    unsigned uhi = (unsigned)__builtin_bit_cast(unsigned short, (bf16)h1);
    ast(hnext + cb * 256 + s * 8 + cjj, ulo | (uhi << 16));

    __syncthreads();            // per-wave vmcnt(0) drain -> h stores visible
    if (tid == 0) ast(flg + s, (unsigned)(step + 1));   // signal (no RMW)

    // overlap with barrier wait: out store + next-step P prefetch
    *(float2*)(out + (size_t)(cb * 512 + trc) * 1024 + dir * 512 + s * 16 + cj) =
        make_float2(h0, h1);
    if (step < 511) {
      trc = dir ? ((510 - step + lenL[cb]) & 511) : (step + 1);
      const float* Pp = P + ((size_t)(dir * 512 + trc) * 32 + cb) * 2048 + s * 64 + cjj * 8;
      p0 = ((const float4*)Pp)[0];
      p1 = ((const float4*)Pp)[1];
      if (wave == 0) {
        unsigned target = (unsigned)(step + 1);
        bool done;
        do {
          unsigned v = (lane < 32) ? ald(flg + lane) : target;
          done = __all((int)(v >= target));
          if (!done) __builtin_amdgcn_s_sleep(1);
        } while (!done);
      }
      __syncthreads();
    }
  }
}

// ---------------- fallback: R4's proven fused kernel ----------------
__global__ __launch_bounds__(256, 1) void lstm_fused(
    const float* __restrict__ x,
    const float* __restrict__ Wih_f, const float* __restrict__ bih_f,
    const float* __restrict__ Whh_f,
    const float* __restrict__ Wih_b, const float* __restrict__ bih_b,
    const float* __restrict__ Whh_b,
    const int* __restrict__ lengths,
    unsigned* __restrict__ hbuf,
    unsigned* __restrict__ barcnt,
    float* __restrict__ out) {
  const int s = blockIdx.x;
  const int dir = blockIdx.y;
  const float* Wih = dir ? Wih_b : Wih_f;
  const float* Whh = dir ? Whh_b : Whh_f;
  const float* bih = dir ? bih_b : bih_f;
  unsigned* cnt = barcnt + dir * 64;

  const int tid = threadIdx.x;
  const int lane = tid & 63, wave = tid >> 6;
  const int l15 = lane & 15, quad = lane >> 4;

  __shared__ __align__(16) bf16 xA[32 * 512];
  __shared__ __align__(16) bf16 hA[32 * 512];
  __shared__ float vbuf[4][32][17];
  __shared__ int lenL[32];

  bf16x8 wih[16], whh[16];
  {
    int grow = wave * 512 + s * 16 + l15;
#pragma unroll
    for (int k = 0; k < 16; ++k) {
      const float* pw = Wih + (size_t)grow * 512 + k * 32 + quad * 8;
      const float* ph = Whh + (size_t)grow * 512 + k * 32 + quad * 8;
      wih[k] = cvt8v(*(const float4*)pw, *(const float4*)(pw + 4));
      whh[k] = cvt8v(*(const float4*)ph, *(const float4*)(ph + 4));
    }
  }
  const float bv = bih[wave * 512 + s * 16 + l15];
  if (tid < 32) lenL[tid] = lengths[tid];
  __syncthreads();

  const int cb = tid >> 3, cj = (tid & 7) * 2;
  float creg0 = 0.f, creg1 = 0.f;
  unsigned* hb = hbuf + dir * (2 * 32 * 256);

  float4 xp[8][2];
#pragma unroll
  for (int i = 0; i < 8; ++i) {
    int c = i * 256 + tid;
    int m = c >> 6, kbp = c & 63;
    int kb = kbp ^ (m & 7);
    int tr = (dir == 0) ? 0 : ((511 + lenL[m]) & 511);
    const float4* p = (const float4*)(x + ((size_t)m * 512 + tr) * 512 + kb * 8);
    xp[i][0] = p[0]; xp[i][1] = p[1];
  }

  for (int step = 0; step < 512; ++step) {
    const int par = step & 1;
    const unsigned* hprev = hb + par * (32 * 256);
    unsigned* hnext = hb + (par ^ 1) * (32 * 256);
#pragma unroll
    for (int i = 0; i < 8; ++i) {
      int c = i * 256 + tid;
      int m = c >> 6, kbp = c & 63;
      int kb = kbp ^ (m & 7);
      const unsigned* hp = hprev + m * 256 + kb * 4;
      uint4 d;
      d.x = ald(hp); d.y = ald(hp + 1); d.z = ald(hp + 2); d.w = ald(hp + 3);
      *(uint4*)(hA + c * 8) = d;
    }
#pragma unroll
    for (int i = 0; i < 8; ++i) {
      int c = i * 256 + tid;
      *(bf16x8*)(xA + c * 8) = cvt8v(xp[i][0], xp[i][1]);
    }
    __syncthreads();

    f32x4 acc0 = {bv, bv, bv, bv};
    f32x4 acc1 = {bv, bv, bv, bv};
#pragma unroll
    for (int k = 0; k < 16; ++k) {
      int kb = k * 4 + quad;
      int sw = (kb ^ (l15 & 7)) * 8;
      bf16x8 ax0 = *(const bf16x8*)(xA + l15 * 512 + sw);
      bf16x8 ah0 = *(const bf16x8*)(hA + l15 * 512 + sw);
      bf16x8 ax1 = *(const bf16x8*)(xA + (16 + l15) * 512 + sw);
      bf16x8 ah1 = *(const bf16x8*)(hA + (16 + l15) * 512 + sw);
      acc0 = __builtin_amdgcn_mfma_f32_16x16x32_bf16(ax0, wih[k], acc0, 0, 0, 0);
      acc0 = __builtin_amdgcn_mfma_f32_16x16x32_bf16(ah0, whh[k], acc0, 0, 0, 0);
      acc1 = __builtin_amdgcn_mfma_f32_16x16x32_bf16(ax1, wih[k], acc1, 0, 0, 0);
      acc1 = __builtin_amdgcn_mfma_f32_16x16x32_bf16(ah1, whh[k], acc1, 0, 0, 0);
    }
#pragma unroll
    for (int r = 0; r < 4; ++r) {
      vbuf[wave][quad * 4 + r][l15] = acc0[r];
      vbuf[wave][16 + quad * 4 + r][l15] = acc1[r];
    }
    __syncthreads();

    float i0 = vbuf[0][cb][cj],     f0 = vbuf[1][cb][cj];
    float g0 = vbuf[2][cb][cj],     o0 = vbuf[3][cb][cj];
    float i1 = vbuf[0][cb][cj + 1], f1 = vbuf[1][cb][cj + 1];
    float g1 = vbuf[2][cb][cj + 1], o1 = vbuf[3][cb][cj + 1];
    float c0 = sigmoidf_(f0) * creg0 + sigmoidf_(i0) * tanhf_(g0);
    float c1 = sigmoidf_(f1) * creg1 + sigmoidf_(i1) * tanhf_(g1);
    creg0 = c0; creg1 = c1;
    float h0 = tanhf_(c0) * sigmoidf_(o0);
    float h1 = tanhf_(c1) * sigmoidf_(o1);
    unsigned ulo = (unsigned)__builtin_bit_cast(unsigned short, (bf16)h0);
    unsigned uhi = (unsigned)__builtin_bit_cast(unsigned short, (bf16)h1);
    ast(hnext + cb * 256 + s * 8 + (tid & 7), ulo | (uhi << 16));

    __syncthreads();
    if (tid == 0)
      __hip_atomic_fetch_add(cnt, 1u, __ATOMIC_RELAXED, __HIP_MEMORY_SCOPE_AGENT);
    {
      int tr = (dir == 0) ? step : ((511 - step + lenL[cb]) & 511);
      *(float2*)(out + (size_t)(cb * 512 + tr) * 1024 + dir * 512 + s * 16 + cj) =
          make_float2(h0, h1);
    }
    if (step < 511) {
#pragma unroll
      for (int i = 0; i < 8; ++i) {
        int c = i * 256 + tid;
        int m = c >> 6, kbp = c & 63;
        int kb = kbp ^ (m & 7);
        int tr = (dir == 0) ? (step + 1) : ((510 - step + lenL[m]) & 511);
        const float4* p = (const float4*)(x + ((size_t)m * 512 + tr) * 512 + kb * 8);
        xp[i][0] = p[0]; xp[i][1] = p[1];
      }
      if (tid == 0) {
        unsigned target = 32u * (unsigned)(step + 1);
        while (ald(cnt) < target) __builtin_amdgcn_s_sleep(1);
      }
      __syncthreads();
    }
  }
}

extern "C" void kernel_launch(void* const* d_in, const int* in_sizes, int n_in,
                              void* d_out, int out_size, void* d_ws, size_t ws_size,
                              hipStream_t stream) {
  (void)in_sizes; (void)n_in; (void)out_size;
  const float* x    = (const float*)d_in[0];
  const int*   mask = (const int*)  d_in[1];
  const float* Wihf = (const float*)d_in[2];
  const float* bihf = (const float*)d_in[3];
  const float* Whhf = (const float*)d_in[4];
  const float* Wihb = (const float*)d_in[5];
  const float* bihb = (const float*)d_in[6];
  const float* Whhb = (const float*)d_in[7];
  float* out = (float*)d_out;

  char* ws = (char*)d_ws;
  unsigned* flags = (unsigned*)ws;            // [2][32] dwords (also barcnt in fallback)
  int* lengths = (int*)(ws + 512);
  unsigned* hbuf = (unsigned*)(ws + 1024);    // 131072 B
  const size_t head = 1024 + (size_t)2 * 2 * 32 * 256 * sizeof(unsigned);
  const size_t Poff = (head + 255) & ~(size_t)255;
  const size_t Pbytes = (size_t)2 * 512 * 32 * 2048 * sizeof(float);  // 256 MB
  float* P = (float*)(ws + Poff);

  hipMemsetAsync(d_ws, 0, head, stream);
  lengths_kernel<<<1, 256, 0, stream>>>(mask, lengths);

  if (ws_size >= Poff + Pbytes) {
    xproj<<<dim3(16, 2, 16), 256, 0, stream>>>(x, Wihf, bihf, Wihb, bihb, P);
    lstm_rec<<<dim3(32, 2), 256, 0, stream>>>(Whhf, Whhb, P, lengths, hbuf, flags, out);
  } else {
    lstm_fused<<<dim3(32, 2), 256, 0, stream>>>(
        x, Wihf, bihf, Whhf, Wihb, bihb, Whhb, lengths, hbuf, flags, out);
  }
}

// Round 6
// 2654.882 us; speedup vs baseline: 1.0787x; 1.0787x over previous
//
#include <hip/hip_runtime.h>
#include <hip/hip_bf16.h>

// Bidirectional LSTM, B=32 T=512 D=H=512. f32 I/O, bf16 MFMA internally.
//
// Persistent fused kernel (no large-workspace dependency), grid=(32,2).
// R6 changes vs R4/R5-fallback:
//  - Barrier = flag ARRAY, no RMW: wg s stores flags[dir][s]=step+1 (relaxed
//    agent, distinct dwords in one LLC line); ALL waves poll the 32 flags with
//    a single parallel 32-lane coherent load + __all, then proceed straight to
//    their own h loads (post-poll __syncthreads eliminated).
//  - out-store issued together with h-store so one vmcnt drain covers both.
//  - h loads are 8B relaxed-atomic loads (half the load count).
//  - 3 __syncthreads/step (stage, vbuf, drain) instead of 4.

typedef __bf16 bf16;
typedef __attribute__((ext_vector_type(8))) __bf16 bf16x8;
typedef __attribute__((ext_vector_type(4))) float f32x4;

__device__ __forceinline__ float sigmoidf_(float x) {
  return 1.f / (1.f + __expf(-x));
}
__device__ __forceinline__ float tanhf_(float x) {
  float e = __expf(-2.f * fabsf(x));
  return copysignf((1.f - e) / (1.f + e), x);
}
__device__ __forceinline__ unsigned ald(const unsigned* p) {
  return __hip_atomic_load(p, __ATOMIC_RELAXED, __HIP_MEMORY_SCOPE_AGENT);
}
__device__ __forceinline__ unsigned long long ald64(const unsigned long long* p) {
  return __hip_atomic_load(p, __ATOMIC_RELAXED, __HIP_MEMORY_SCOPE_AGENT);
}
__device__ __forceinline__ void ast(unsigned* p, unsigned v) {
  __hip_atomic_store(p, v, __ATOMIC_RELAXED, __HIP_MEMORY_SCOPE_AGENT);
}
__device__ __forceinline__ bf16x8 cvt8v(float4 a, float4 b) {
  bf16x8 v;
  v[0] = (bf16)a.x; v[1] = (bf16)a.y; v[2] = (bf16)a.z; v[3] = (bf16)a.w;
  v[4] = (bf16)b.x; v[5] = (bf16)b.y; v[6] = (bf16)b.z; v[7] = (bf16)b.w;
  return v;
}

// ---------------- lengths ----------------
__global__ void lengths_kernel(const int* __restrict__ mask, int* __restrict__ lengths) {
  __shared__ int part[32][8];
  int t = threadIdx.x;
  int b = t >> 3, sub = t & 7;
  int s = 0;
#pragma unroll 8
  for (int k = 0; k < 64; ++k) s += mask[b * 512 + sub + 8 * k];
  part[b][sub] = s;
  __syncthreads();
  if (sub == 0) {
    int tot = 0;
#pragma unroll
    for (int k = 0; k < 8; ++k) tot += part[b][k];
    lengths[b] = tot;
  }
}

// ---------------- fused persistent LSTM ----------------
__global__ __launch_bounds__(256, 1) void lstm_fused(
    const float* __restrict__ x,                                  // [32][512][512] f32
    const float* __restrict__ Wih_f, const float* __restrict__ bih_f,
    const float* __restrict__ Whh_f,
    const float* __restrict__ Wih_b, const float* __restrict__ bih_b,
    const float* __restrict__ Whh_b,
    const int* __restrict__ lengths,
    unsigned* __restrict__ hbuf,        // [2 dir][2 par][32][256] dwords (2 bf16 each)
    unsigned* __restrict__ flags,       // [2][64] dwords; wg s of dir uses flags[dir*64+s]
    float* __restrict__ out) {          // [32][512][1024] f32
  const int s = blockIdx.x;             // h-col slice: cols [16s, 16s+16)
  const int dir = blockIdx.y;
  const float* Wih = dir ? Wih_b : Wih_f;
  const float* Whh = dir ? Whh_b : Whh_f;
  const float* bih = dir ? bih_b : bih_f;
  unsigned* flg = flags + dir * 64;

  const int tid = threadIdx.x;
  const int lane = tid & 63, wave = tid >> 6;
  const int l15 = lane & 15, quad = lane >> 4;

  __shared__ __align__(16) bf16 xA[32 * 512];   // 32 KB, XOR-swizzled chunks
  __shared__ __align__(16) bf16 hA[32 * 512];   // 32 KB
  __shared__ float vbuf[4][32][17];
  __shared__ int lenL[32];

  // Weight slices f32 -> bf16 registers (B-frag layout: k=quad*8+j, n=l15).
  bf16x8 wih[16], whh[16];
  {
    int grow = wave * 512 + s * 16 + l15;
#pragma unroll
    for (int k = 0; k < 16; ++k) {
      const float* pw = Wih + (size_t)grow * 512 + k * 32 + quad * 8;
      const float* ph = Whh + (size_t)grow * 512 + k * 32 + quad * 8;
      wih[k] = cvt8v(*(const float4*)pw, *(const float4*)(pw + 4));
      whh[k] = cvt8v(*(const float4*)ph, *(const float4*)(ph + 4));
    }
  }
  const float bv = bih[wave * 512 + s * 16 + l15];
  if (tid < 32) lenL[tid] = lengths[tid];
  __syncthreads();

  const int cb = tid >> 3, cj = (tid & 7) * 2;
  float creg0 = 0.f, creg1 = 0.f;
  unsigned* hb = hbuf + dir * (2 * 32 * 256);

  // x prefetch registers for step 0
  float4 xp[8][2];
#pragma unroll
  for (int i = 0; i < 8; ++i) {
    int c = i * 256 + tid;
    int m = c >> 6, kbp = c & 63;
    int kb = kbp ^ (m & 7);
    int tr = (dir == 0) ? 0 : ((511 + lenL[m]) & 511);
    const float4* p = (const float4*)(x + ((size_t)m * 512 + tr) * 512 + kb * 8);
    xp[i][0] = p[0]; xp[i][1] = p[1];
  }

  for (int step = 0; step < 512; ++step) {
    const int par = step & 1;
    const unsigned* hprev = hb + par * (32 * 256);
    unsigned* hnext = hb + (par ^ 1) * (32 * 256);

    // stage h (8B coherent loads) + x (cvt from prefetched regs) -> swizzled LDS
#pragma unroll
    for (int i = 0; i < 8; ++i) {
      int c = i * 256 + tid;
      int m = c >> 6, kbp = c & 63;
      int kb = kbp ^ (m & 7);
      const unsigned long long* hp =
          (const unsigned long long*)(hprev + m * 256 + kb * 4);
      unsigned long long d0 = ald64(hp), d1 = ald64(hp + 1);
      *(unsigned long long*)(hA + c * 8) = d0;
      *(unsigned long long*)(hA + c * 8 + 4) = d1;
    }
#pragma unroll
    for (int i = 0; i < 8; ++i) {
      int c = i * 256 + tid;
      *(bf16x8*)(xA + c * 8) = cvt8v(xp[i][0], xp[i][1]);
    }
    __syncthreads();   // staging ready (drains lgkm + vm per wave)

    // v = x@Wih^T + h@Whh^T + bias
    f32x4 acc0 = {bv, bv, bv, bv};
    f32x4 acc1 = {bv, bv, bv, bv};
#pragma unroll
    for (int k = 0; k < 16; ++k) {
      int kb = k * 4 + quad;
      int sw = (kb ^ (l15 & 7)) * 8;
      bf16x8 ax0 = *(const bf16x8*)(xA + l15 * 512 + sw);
      bf16x8 ah0 = *(const bf16x8*)(hA + l15 * 512 + sw);
      bf16x8 ax1 = *(const bf16x8*)(xA + (16 + l15) * 512 + sw);
      bf16x8 ah1 = *(const bf16x8*)(hA + (16 + l15) * 512 + sw);
      acc0 = __builtin_amdgcn_mfma_f32_16x16x32_bf16(ax0, wih[k], acc0, 0, 0, 0);
      acc0 = __builtin_amdgcn_mfma_f32_16x16x32_bf16(ah0, whh[k], acc0, 0, 0, 0);
      acc1 = __builtin_amdgcn_mfma_f32_16x16x32_bf16(ax1, wih[k], acc1, 0, 0, 0);
      acc1 = __builtin_amdgcn_mfma_f32_16x16x32_bf16(ah1, whh[k], acc1, 0, 0, 0);
    }
#pragma unroll
    for (int r = 0; r < 4; ++r) {
      vbuf[wave][quad * 4 + r][l15] = acc0[r];
      vbuf[wave][16 + quad * 4 + r][l15] = acc1[r];
    }
    __syncthreads();

    // cell update
    float i0 = vbuf[0][cb][cj],     f0 = vbuf[1][cb][cj];
    float g0 = vbuf[2][cb][cj],     o0 = vbuf[3][cb][cj];
    float i1 = vbuf[0][cb][cj + 1], f1 = vbuf[1][cb][cj + 1];
    float g1 = vbuf[2][cb][cj + 1], o1 = vbuf[3][cb][cj + 1];
    float c0 = sigmoidf_(f0) * creg0 + sigmoidf_(i0) * tanhf_(g0);
    float c1 = sigmoidf_(f1) * creg1 + sigmoidf_(i1) * tanhf_(g1);
    creg0 = c0; creg1 = c1;
    float h0 = tanhf_(c0) * sigmoidf_(o0);
    float h1 = tanhf_(c1) * sigmoidf_(o1);
    unsigned ulo = (unsigned)__builtin_bit_cast(unsigned short, (bf16)h0);
    unsigned uhi = (unsigned)__builtin_bit_cast(unsigned short, (bf16)h1);
    // h store + out store issued together: one drain covers both (overlapped)
    ast(hnext + cb * 256 + s * 8 + (tid & 7), ulo | (uhi << 16));
    int tr = (dir == 0) ? step : ((511 - step + lenL[cb]) & 511);
    *(float2*)(out + (size_t)(cb * 512 + tr) * 1024 + dir * 512 + s * 16 + cj) =
        make_float2(h0, h1);

    if (step < 511) {
      __syncthreads();   // per-wave vmcnt(0) drain -> h (and out) stores visible
      if (tid == 0) ast(flg + s, (unsigned)(step + 1));   // signal own flag (no RMW)

      // next-step x prefetch overlaps the wait
#pragma unroll
      for (int i = 0; i < 8; ++i) {
        int c = i * 256 + tid;
        int m = c >> 6, kbp = c & 63;
        int kb = kbp ^ (m & 7);
        int tr2 = (dir == 0) ? (step + 1) : ((510 - step + lenL[m]) & 511);
        const float4* p = (const float4*)(x + ((size_t)m * 512 + tr2) * 512 + kb * 8);
        xp[i][0] = p[0]; xp[i][1] = p[1];
      }

      // ALL waves poll all 32 flags (parallel 32-lane coherent load + __all);
      // each wave proceeds to its own h loads immediately -> no post-poll sync.
      unsigned target = (unsigned)(step + 1);
      bool done;
      do {
        unsigned v = (lane < 32) ? ald(flg + lane) : target;
        done = __all((int)(v >= target));
        if (!done) __builtin_amdgcn_s_sleep(1);
      } while (!done);
    }
  }
}

extern "C" void kernel_launch(void* const* d_in, const int* in_sizes, int n_in,
                              void* d_out, int out_size, void* d_ws, size_t ws_size,
                              hipStream_t stream) {
  (void)in_sizes; (void)n_in; (void)out_size; (void)ws_size;
  const float* x    = (const float*)d_in[0];
  const int*   mask = (const int*)  d_in[1];
  const float* Wihf = (const float*)d_in[2];
  const float* bihf = (const float*)d_in[3];
  const float* Whhf = (const float*)d_in[4];
  const float* Wihb = (const float*)d_in[5];
  const float* bihb = (const float*)d_in[6];
  const float* Whhb = (const float*)d_in[7];
  float* out = (float*)d_out;

  char* ws = (char*)d_ws;
  unsigned* flags = (unsigned*)ws;            // [2][64] dwords = 512 B
  int* lengths = (int*)(ws + 512);            // 128 B
  unsigned* hbuf = (unsigned*)(ws + 1024);    // 131072 B
  const size_t head = 1024 + (size_t)2 * 2 * 32 * 256 * sizeof(unsigned);

  hipMemsetAsync(d_ws, 0, head, stream);      // re-arm flags + h0 = c0 = 0 every call
  lengths_kernel<<<1, 256, 0, stream>>>(mask, lengths);
  lstm_fused<<<dim3(32, 2), 256, 0, stream>>>(
      x, Wihf, bihf, Whhf, Wihb, bihb, Whhb, lengths, hbuf, flags, out);
}